// Round 8
// baseline (10366.424 us; speedup 1.0000x reference)
//
#include <hip/hip_runtime.h>
#include <math.h>

// ============================================================================
// Seq2Seq decode: fully-fused persistent kernel, v7 = v2 + non-temporal
// weight loads. (Resubmission: R7 bench died infra-side before running —
// same "container failed twice" signature as R1; kernel never executed.)
//
// v2..v6 post-mortem: four different schedules (serialized C loads, 16-wave
// occupancy, depth-3 async LDS DMA ring) all converge to 7.3-8.0 ms, and all
// run the weight stream at ~11-14 B/cyc/CU from L2 (even the R0 baseline
// GEMM did). Depth-3 prefetch with ~4700cyc slack moved nothing -> NOT a
// latency problem; it's a THROUGHPUT cap on the CU's global-read path.
// Most plausible: every weight load is an L1 miss (7.08MB/step streams
// through 32KB L1); L1 miss/fill pipeline sustains ~11 B/cyc.
//
// v7: identical to the verified v2 kernel (7.38ms, absmax 0.00390625) except
// all weight loads use __builtin_nontemporal_load (nt modifier -> bypass L1
// allocation). Weights have zero L1 temporal reuse: the only reuse is
// same-address-within-wave, which merges before L1. One-variable A/B.
//
// Geometry (v2): 512 thr = 8 waves; wave c owns gate-cols [c*128,c*128+128);
// cg=lane&15, rg=lane>>4; thread = 2 units (u0, u0+1 interleaved) x 4
// gates x 4 rows. Repacked weights: quad = q*1024 + c*128 + j*16 + cg, with
// unit-interleaved gate cols j (0..7): W row = (j&3)*256 + u0 + (j>>2).
// lin: quad = q*256 + c*32 + cg.
// LDS X[1152][16]: prob | tags | h0 | h1 | h2 (contiguous K ranges).
// ============================================================================

typedef float v4 __attribute__((ext_vector_type(4)));
typedef float v2f __attribute__((ext_vector_type(2)));

constexpr int Bsz   = 4096;
constexpr int AA    = 256;
constexpr int STEPS = 30;
constexpr int LDP   = 31 * AA;                       // 7936
constexpr long long PROB_N = (long long)Bsz * 31 * AA;

constexpr int WP0_Q = 160 * 1024;                    // L0: K=640
constexpr int WP1_Q = 128 * 1024;                    // L1: K=512
constexpr int WP2_Q = 128 * 1024;                    // L2: K=512
constexpr int WPL_Q = 64 * 256;                      // lin: K=256
constexpr int WP1_BASE = WP0_Q;
constexpr int WP2_BASE = WP1_BASE + WP1_Q;
constexpr int WPL_BASE = WP2_BASE + WP2_Q;
constexpr int WP_TOTAL = WPL_BASE + WPL_Q;           // 442368 quads = 7.08 MB

constexpr int XROWS = 1152;

__device__ __forceinline__ float sigf(float x) { return 1.0f / (1.0f + expf(-x)); }

#define NTL(p) __builtin_nontemporal_load(p)

// ---------------------------------------------------------------------------
// One-time weight repack into wave-contiguous layout (v2 mapping).
// ---------------------------------------------------------------------------
__global__ void repack_kernel(const float* __restrict__ Wih0, const float* __restrict__ Whh0,
                              const float* __restrict__ Wih12, const float* __restrict__ Whh12,
                              const float* __restrict__ linW, float* __restrict__ ws)
{
    int t = blockIdx.x * 256 + threadIdx.x;          // quad index, exact grid
    v4 val;
    if (t < WP1_BASE) {                              // layer 0, fused K = 640
        int cg = t & 15, j = (t >> 4) & 7, cc = (t >> 7) & 7, q = t >> 10;
        int u = cc * 32 + cg * 2 + (j >> 2);
        int grow = (j & 3) * 256 + u;
        int k4 = q * 4;
        const float* src = (k4 < 384) ? (Wih0 + grow * 384 + k4)          // [prob|tags]
                                      : (Whh0 + grow * 256 + (k4 - 384)); // h0
        val = *reinterpret_cast<const v4*>(src);
    } else if (t < WP2_BASE) {                       // layer 1, K = 512
        int tt = t - WP1_BASE;
        int cg = tt & 15, j = (tt >> 4) & 7, cc = (tt >> 7) & 7, q = tt >> 10;
        int u = cc * 32 + cg * 2 + (j >> 2);
        int grow = (j & 3) * 256 + u;
        int k4 = q * 4;
        const float* src = (k4 < 256) ? (Wih12 + grow * 256 + k4)
                                      : (Whh12 + grow * 256 + (k4 - 256));
        val = *reinterpret_cast<const v4*>(src);
    } else if (t < WPL_BASE) {                       // layer 2, K = 512
        int tt = t - WP2_BASE;
        int cg = tt & 15, j = (tt >> 4) & 7, cc = (tt >> 7) & 7, q = tt >> 10;
        int u = cc * 32 + cg * 2 + (j >> 2);
        int grow = (j & 3) * 256 + u;
        int k4 = q * 4;
        const float* src = (k4 < 256) ? (Wih12 + 262144 + grow * 256 + k4)
                                      : (Whh12 + 262144 + grow * 256 + (k4 - 256));
        val = *reinterpret_cast<const v4*>(src);
    } else {                                         // lin, K = 256
        int tt = t - WPL_BASE;
        int cg = tt & 15, j = (tt >> 4) & 1, cc = (tt >> 5) & 7, q = tt >> 8;
        int n = cc * 32 + cg * 2 + j;
        val = *reinterpret_cast<const v4*>(linW + n * 256 + q * 4);
    }
    reinterpret_cast<v4*>(ws)[t] = val;
}

// ---------------------------------------------------------------------------
// LSTM layer phase: GEMM (K = 4*Q) + cell epilogue.
// wq  : repacked weight base + c*128 + cg (quads); per-q stride 1024 quads
// xb  : LDS input [4*Q][16] (contiguous row range of X)
// dst : LDS h dest ([256][16] base inside X)
// ---------------------------------------------------------------------------
template<int Q>
__device__ __forceinline__ void lstm_phase(
    const v4* __restrict__ wq, const float* __restrict__ xb,
    const float* __restrict__ bihL, const float* __restrict__ bhhL,
    int u0, int rg, float (&cr)[2][4], float* __restrict__ dst)
{
    float bs[8];
    #pragma unroll
    for (int j = 0; j < 8; j++) {
        int grow = (j & 3) * 256 + u0 + (j >> 2);
        bs[j] = bihL[grow] + bhhL[grow];
    }
    float acc[8][4];
    #pragma unroll
    for (int j = 0; j < 8; j++)
        #pragma unroll
        for (int r = 0; r < 4; r++) acc[j][r] = 0.0f;

    const v4* xq = reinterpret_cast<const v4*>(xb) + rg;
    v4 wa[8], wb[8], xa[4], xc[4];

    #pragma unroll
    for (int j = 0; j < 8; j++) wa[j] = NTL(&wq[j * 16]);
    #pragma unroll
    for (int k = 0; k < 4; k++) xa[k] = xq[k * 4];

    #pragma unroll 1
    for (int q = 0; q < Q - 2; q += 2) {
        #pragma unroll
        for (int j = 0; j < 8; j++) wb[j] = NTL(&wq[(q + 1) * 1024 + j * 16]);
        #pragma unroll
        for (int k = 0; k < 4; k++) xc[k] = xq[((q + 1) * 4 + k) * 4];
        #pragma unroll
        for (int k = 0; k < 4; k++)
            #pragma unroll
            for (int j = 0; j < 8; j++)
                #pragma unroll
                for (int r = 0; r < 4; r++)
                    acc[j][r] += wa[j][k] * xa[k][r];
        #pragma unroll
        for (int j = 0; j < 8; j++) wa[j] = NTL(&wq[(q + 2) * 1024 + j * 16]);
        #pragma unroll
        for (int k = 0; k < 4; k++) xa[k] = xq[((q + 2) * 4 + k) * 4];
        #pragma unroll
        for (int k = 0; k < 4; k++)
            #pragma unroll
            for (int j = 0; j < 8; j++)
                #pragma unroll
                for (int r = 0; r < 4; r++)
                    acc[j][r] += wb[j][k] * xc[k][r];
    }
    // tail: chunk Q-2 (already in wa/xa) and chunk Q-1
    #pragma unroll
    for (int j = 0; j < 8; j++) wb[j] = NTL(&wq[(Q - 1) * 1024 + j * 16]);
    #pragma unroll
    for (int k = 0; k < 4; k++) xc[k] = xq[((Q - 1) * 4 + k) * 4];
    #pragma unroll
    for (int k = 0; k < 4; k++)
        #pragma unroll
        for (int j = 0; j < 8; j++)
            #pragma unroll
            for (int r = 0; r < 4; r++)
                acc[j][r] += wa[j][k] * xa[k][r];
    #pragma unroll
    for (int k = 0; k < 4; k++)
        #pragma unroll
        for (int j = 0; j < 8; j++)
            #pragma unroll
            for (int r = 0; r < 4; r++)
                acc[j][r] += wb[j][k] * xc[k][r];

    __syncthreads();   // all waves done READING xb before h region is overwritten
    #pragma unroll
    for (int ul = 0; ul < 2; ul++) {
        int u = u0 + ul;
        v4 hv;
        #pragma unroll
        for (int r = 0; r < 4; r++) {
            float gi = acc[ul * 4 + 0][r] + bs[ul * 4 + 0];
            float gf = acc[ul * 4 + 1][r] + bs[ul * 4 + 1];
            float gg = acc[ul * 4 + 2][r] + bs[ul * 4 + 2];
            float go = acc[ul * 4 + 3][r] + bs[ul * 4 + 3];
            float cn = sigf(gf) * cr[ul][r] + sigf(gi) * tanhf(gg);
            cr[ul][r] = cn;
            hv[r] = sigf(go) * tanhf(cn);
        }
        *reinterpret_cast<v4*>(dst + u * 16 + rg * 4) = hv;
    }
    __syncthreads();   // h visible before next phase reads it
}

// ---------------------------------------------------------------------------
// lin phase: pred = sigmoid(h2 @ linW^T + b); writes prob LDS + global out.
// Q = 64, per-q stride 256 quads; thread cols = u0, u0+1.
// ---------------------------------------------------------------------------
__device__ __forceinline__ void lin_phase(
    const v4* __restrict__ wq, const float* __restrict__ xb,
    const float* __restrict__ linb,
    int u0, int rg, int m0, int t,
    float* __restrict__ probdst, float* __restrict__ out)
{
    float bs[2] = { linb[u0], linb[u0 + 1] };
    float acc[2][4];
    #pragma unroll
    for (int j = 0; j < 2; j++)
        #pragma unroll
        for (int r = 0; r < 4; r++) acc[j][r] = 0.0f;

    const v4* xq = reinterpret_cast<const v4*>(xb) + rg;
    v4 wa[2], wb[2], xa[4], xc[4];
    #pragma unroll
    for (int j = 0; j < 2; j++) wa[j] = NTL(&wq[j * 16]);
    #pragma unroll
    for (int k = 0; k < 4; k++) xa[k] = xq[k * 4];

    #pragma unroll 1
    for (int q = 0; q < 62; q += 2) {
        #pragma unroll
        for (int j = 0; j < 2; j++) wb[j] = NTL(&wq[(q + 1) * 256 + j * 16]);
        #pragma unroll
        for (int k = 0; k < 4; k++) xc[k] = xq[((q + 1) * 4 + k) * 4];
        #pragma unroll
        for (int k = 0; k < 4; k++)
            #pragma unroll
            for (int j = 0; j < 2; j++)
                #pragma unroll
                for (int r = 0; r < 4; r++)
                    acc[j][r] += wa[j][k] * xa[k][r];
        #pragma unroll
        for (int j = 0; j < 2; j++) wa[j] = NTL(&wq[(q + 2) * 256 + j * 16]);
        #pragma unroll
        for (int k = 0; k < 4; k++) xa[k] = xq[((q + 2) * 4 + k) * 4];
        #pragma unroll
        for (int k = 0; k < 4; k++)
            #pragma unroll
            for (int j = 0; j < 2; j++)
                #pragma unroll
                for (int r = 0; r < 4; r++)
                    acc[j][r] += wb[j][k] * xc[k][r];
    }
    #pragma unroll
    for (int j = 0; j < 2; j++) wb[j] = NTL(&wq[63 * 256 + j * 16]);
    #pragma unroll
    for (int k = 0; k < 4; k++) xc[k] = xq[(63 * 4 + k) * 4];
    #pragma unroll
    for (int k = 0; k < 4; k++)
        #pragma unroll
        for (int j = 0; j < 2; j++)
            #pragma unroll
            for (int r = 0; r < 4; r++)
                acc[j][r] += wa[j][k] * xa[k][r];
    #pragma unroll
    for (int k = 0; k < 4; k++)
        #pragma unroll
        for (int j = 0; j < 2; j++)
            #pragma unroll
            for (int r = 0; r < 4; r++)
                acc[j][r] += wb[j][k] * xc[k][r];

    __syncthreads();   // everyone done reading h2; old prob no longer needed
    v4 pv[2];
    #pragma unroll
    for (int j = 0; j < 2; j++) {
        #pragma unroll
        for (int r = 0; r < 4; r++) pv[j][r] = sigf(acc[j][r] + bs[j]);
        *reinterpret_cast<v4*>(probdst + (u0 + j) * 16 + rg * 4) = pv[j];
    }
    #pragma unroll
    for (int r = 0; r < 4; r++) {
        v2f f2; f2[0] = pv[0][r]; f2[1] = pv[1][r];
        *reinterpret_cast<v2f*>(out + (long long)(m0 + rg * 4 + r) * LDP
                                    + (long long)(t + 1) * AA + u0) = f2;
    }
    __syncthreads();   // prob LDS visible for argmax + next step
}

// ---------------------------------------------------------------------------
// Persistent decode kernel: 256 blocks x 16 rows, 30 steps fused.
// ---------------------------------------------------------------------------
__global__ __launch_bounds__(512) void decode_kernel(
    const float* __restrict__ tags,
    const float* __restrict__ bih0, const float* __restrict__ bhh0,
    const float* __restrict__ bih12, const float* __restrict__ bhh12,
    const float* __restrict__ linb,
    const float* __restrict__ ws,
    float* __restrict__ out)
{
    __shared__ float X[XROWS * 16];      // 73728 B
    __shared__ float redv[512];          // argmax partials
    __shared__ int   redi[512];

    const int tid  = threadIdx.x;
    const int c    = tid >> 6;
    const int lane = tid & 63;
    const int cg   = lane & 15;
    const int rg   = lane >> 4;
    const int u0   = c * 32 + cg * 2;
    const int m0   = blockIdx.x * 16;

    // ---- init: zero state, stage tags, one-hot(START=1) ----
    for (int i = tid; i < XROWS * 16; i += 512) X[i] = 0.0f;
    __syncthreads();
    for (int i = tid; i < 128 * 16; i += 512) {
        int m = i & 15, k = i >> 4;
        X[(256 + k) * 16 + m] = tags[(long long)(m0 + m) * 128 + k];
    }
    if (tid < 16) X[1 * 16 + tid] = 1.0f;                    // prob one-hot col 1
    for (int i = tid; i < 256 * 16; i += 512) {
        int m = i >> 8, col = i & 255;
        out[(long long)(m0 + m) * LDP + col] = (col == 1) ? 1.0f : 0.0f;
    }
    __syncthreads();

    float cr0[2][4], cr1[2][4], cr2[2][4];
    #pragma unroll
    for (int a = 0; a < 2; a++)
        #pragma unroll
        for (int b = 0; b < 4; b++) { cr0[a][b] = 0.f; cr1[a][b] = 0.f; cr2[a][b] = 0.f; }

    const v4* wsq = reinterpret_cast<const v4*>(ws);
    const v4* w0 = wsq + 0        + c * 128 + cg;
    const v4* w1 = wsq + WP1_BASE + c * 128 + cg;
    const v4* w2 = wsq + WP2_BASE + c * 128 + cg;
    const v4* wl = wsq + WPL_BASE + c * 32  + cg;

    float* hx0 = X + 384 * 16;   // h0 rows
    float* hx1 = X + 640 * 16;   // h1 rows
    float* hx2 = X + 896 * 16;   // h2 rows

    const int arow = tid & 15, sb = tid >> 4;
    float* outputs = out + PROB_N;

    #pragma unroll 1
    for (int t = 0; t < STEPS; t++) {
        lstm_phase<160>(w0, X,   bih0,         bhh0,         u0, rg, cr0, hx0);
        lstm_phase<128>(w1, hx0, bih12,        bhh12,        u0, rg, cr1, hx1);
        lstm_phase<128>(w2, hx1, bih12 + 1024, bhh12 + 1024, u0, rg, cr2, hx2);
        lin_phase(wl, hx2, linb, u0, rg, m0, t, X, out);

        // ---- argmax over X[0..255][arow] (prob), first-max tie rule ----
        float bv = -1.0f; int bi = 0;
        #pragma unroll
        for (int i = 0; i < 8; i++) {
            int uu = sb * 8 + i;
            float v = X[uu * 16 + arow];
            if (v > bv) { bv = v; bi = uu; }
        }
        redv[sb * 16 + arow] = bv;
        redi[sb * 16 + arow] = bi;
        __syncthreads();
        if (tid < 16) {
            float v0 = redv[tid]; int i0 = redi[tid];
            #pragma unroll 1
            for (int s = 1; s < 32; s++) {
                float v = redv[s * 16 + tid]; int ii = redi[s * 16 + tid];
                if (v > v0 || (v == v0 && ii < i0)) { v0 = v; i0 = ii; }
            }
            outputs[(long long)(m0 + tid) * STEPS + t] = (float)i0;
        }
        // no extra barrier needed: redv/redi next written only after the 8
        // barriers of step t+1's phases; prob/h reads below are read-read.
    }
}

// ---------------------------------------------------------------------------
extern "C" void kernel_launch(void* const* d_in, const int* in_sizes, int n_in,
                              void* d_out, int out_size, void* d_ws, size_t ws_size,
                              hipStream_t stream) {
    const float* tags  = (const float*)d_in[2];
    const float* Wih0  = (const float*)d_in[13];  // [1024, 384]
    const float* Whh0  = (const float*)d_in[14];  // [1024, 256]
    const float* bih0  = (const float*)d_in[15];
    const float* bhh0  = (const float*)d_in[16];
    const float* Wih12 = (const float*)d_in[17];  // [2, 1024, 256]
    const float* Whh12 = (const float*)d_in[18];
    const float* bih12 = (const float*)d_in[19];  // [2, 1024]
    const float* bhh12 = (const float*)d_in[20];
    const float* linW  = (const float*)d_in[21];  // [256, 256]
    const float* linb  = (const float*)d_in[22];

    float* out = (float*)d_out;
    float* ws  = (float*)d_ws;                    // 7.08 MB repacked weights

    repack_kernel<<<WP_TOTAL / 256, 256, 0, stream>>>(Wih0, Whh0, Wih12, Whh12,
                                                      linW, ws);
    decode_kernel<<<Bsz / 16, 512, 0, stream>>>(
        tags, bih0, bhh0, bih12, bhh12, linb, ws, out);
}

// Round 9
// 6878.585 us; speedup vs baseline: 1.5071x; 1.5071x over previous
//
#include <hip/hip_runtime.h>
#include <math.h>

// ============================================================================
// Seq2Seq decode: fully-fused persistent kernel, v9 — 8x8 thread tile.
//
// v2..v8 post-mortem: the wall (7.3-8.0ms) is BYTES-PER-FMA through the two
// register-fill pipes, invariant under scheduling: v2 = w@1B/FMA via L1
// return (~26.6MB/CU/step = observed wall); v5 = w+x@2B/FMA via LDS pipe
// (660K cyc = observed wall); v8-nt proved L2 absorption matters (bypass ->
// 16GB FETCH, 10.4ms). Only a bigger per-thread tile cuts B/FMA.
//
// v9: 256 blocks x 256 threads (4 waves); block = 16 rows x 1024 gatecols
// (full width: NO inter-block coupling). Thread = 8 rows x 8 gatecols
// (2 units x 4 gates): w = 0.5 B/FMA via L1-return (~222K cyc/CU/step),
// x = 0.5 B/FMA via LDS (~167K) -- balanced on separate pipes, each ~= the
// VALU floor (221K/SIMD/step). __launch_bounds__(256,1) -> 512-VGPR budget
// so the w/x double-buffers actually stay in registers (the v3/v4 failure).
// Per-output accumulation order unchanged (k ascending, fp32 fma) ->
// absmax must stay exactly 0.00390625.
//
// Geometry: wave w (0..3) owns gatecol-slice [w*256, +256); lane: cg=lane&31,
// rg=lane>>5; thread = units {w*64+cg, w*64+32+cg} x 4 gates x rows
// [rg*8, rg*8+8). Virtual col j (0..7): W row = (j&3)*256 + u0 + (j>>2)*32.
// Repacked weights (float4 quads along k): quad = q*1024 + w*256 + j*32 + cg
//   -> per (q,j) a wave reads 32 consecutive quads = 512B, coalesced.
// lin: quad = q*256 + w*64 + jl*32 + cg (col n = w*64 + jl*32 + cg).
// LDS X[1152][16] identical to v2: prob | tags | h0 | h1 | h2.
// ============================================================================

typedef float v4 __attribute__((ext_vector_type(4)));

constexpr int Bsz   = 4096;
constexpr int AA    = 256;
constexpr int STEPS = 30;
constexpr int LDP   = 31 * AA;                       // 7936
constexpr long long PROB_N = (long long)Bsz * 31 * AA;

constexpr int WP0_Q = 160 * 1024;                    // L0: K=640
constexpr int WP1_Q = 128 * 1024;                    // L1: K=512
constexpr int WP2_Q = 128 * 1024;                    // L2: K=512
constexpr int WPL_Q = 64 * 256;                      // lin: K=256
constexpr int WP1_BASE = WP0_Q;
constexpr int WP2_BASE = WP1_BASE + WP1_Q;
constexpr int WPL_BASE = WP2_BASE + WP2_Q;
constexpr int WP_TOTAL = WPL_BASE + WPL_Q;           // 442368 quads = 7.08 MB

constexpr int XROWS = 1152;

__device__ __forceinline__ float sigf(float x) { return 1.0f / (1.0f + expf(-x)); }

// ---------------------------------------------------------------------------
// One-time weight repack into wave-contiguous layout (v9 mapping).
// ---------------------------------------------------------------------------
__global__ void repack_kernel(const float* __restrict__ Wih0, const float* __restrict__ Whh0,
                              const float* __restrict__ Wih12, const float* __restrict__ Whh12,
                              const float* __restrict__ linW, float* __restrict__ ws)
{
    int t = blockIdx.x * 256 + threadIdx.x;          // quad index, exact grid
    v4 val;
    if (t < WP1_BASE) {                              // layer 0, fused K = 640
        int cg = t & 31, j = (t >> 5) & 7, w = (t >> 8) & 3, q = t >> 10;
        int grow = (j & 3) * 256 + w * 64 + (j >> 2) * 32 + cg;
        int k4 = q * 4;
        const float* src = (k4 < 384) ? (Wih0 + grow * 384 + k4)          // [prob|tags]
                                      : (Whh0 + grow * 256 + (k4 - 384)); // h0
        val = *reinterpret_cast<const v4*>(src);
    } else if (t < WP2_BASE) {                       // layer 1, K = 512
        int tt = t - WP1_BASE;
        int cg = tt & 31, j = (tt >> 5) & 7, w = (tt >> 8) & 3, q = tt >> 10;
        int grow = (j & 3) * 256 + w * 64 + (j >> 2) * 32 + cg;
        int k4 = q * 4;
        const float* src = (k4 < 256) ? (Wih12 + grow * 256 + k4)
                                      : (Whh12 + grow * 256 + (k4 - 256));
        val = *reinterpret_cast<const v4*>(src);
    } else if (t < WPL_BASE) {                       // layer 2, K = 512
        int tt = t - WP2_BASE;
        int cg = tt & 31, j = (tt >> 5) & 7, w = (tt >> 8) & 3, q = tt >> 10;
        int grow = (j & 3) * 256 + w * 64 + (j >> 2) * 32 + cg;
        int k4 = q * 4;
        const float* src = (k4 < 256) ? (Wih12 + 262144 + grow * 256 + k4)
                                      : (Whh12 + 262144 + grow * 256 + (k4 - 256));
        val = *reinterpret_cast<const v4*>(src);
    } else {                                         // lin, K = 256
        int tt = t - WPL_BASE;
        int cg = tt & 31, jl = (tt >> 5) & 1, w = (tt >> 6) & 3, q = tt >> 8;
        int n = w * 64 + jl * 32 + cg;
        val = *reinterpret_cast<const v4*>(linW + n * 256 + q * 4);
    }
    reinterpret_cast<v4*>(ws)[t] = val;
}

// one chunk of FMAs: 4k x 8j x (2 row-quads x 4) = 256 fma
#define FMA_CHUNK(W, Xv)                                          \
    _Pragma("unroll") for (int k = 0; k < 4; k++)                 \
        _Pragma("unroll") for (int j = 0; j < 8; j++)             \
            _Pragma("unroll") for (int h = 0; h < 2; h++)         \
                _Pragma("unroll") for (int r = 0; r < 4; r++)     \
                    acc[j][h * 4 + r] += W[j][k] * Xv[k][h][r];

// ---------------------------------------------------------------------------
// LSTM layer phase: GEMM (K = 4*Q) + cell epilogue. Thread = 8 rows x 8 cols.
// wq: repacked base + w*256 + cg (quads); chunk stride 1024 quads.
// xb: LDS input [4*Q][16]; dst: LDS h dest ([256][16] base inside X).
// ---------------------------------------------------------------------------
template<int Q>
__device__ __forceinline__ void lstm_phase(
    const v4* __restrict__ wq, const float* __restrict__ xb,
    const float* __restrict__ bihL, const float* __restrict__ bhhL,
    int u0, int rg, float (&cr)[2][8], float* __restrict__ dst)
{
    float bs[8];
    #pragma unroll
    for (int j = 0; j < 8; j++) {
        int grow = (j & 3) * 256 + u0 + (j >> 2) * 32;
        bs[j] = bihL[grow] + bhhL[grow];
    }
    float acc[8][8];
    #pragma unroll
    for (int j = 0; j < 8; j++)
        #pragma unroll
        for (int r = 0; r < 8; r++) acc[j][r] = 0.0f;

    const v4* xq = reinterpret_cast<const v4*>(xb) + rg * 2;
    v4 wa[8], wb[8], xa[4][2], xc[4][2];

    #pragma unroll
    for (int j = 0; j < 8; j++) wa[j] = wq[j * 32];
    #pragma unroll
    for (int k = 0; k < 4; k++) {
        xa[k][0] = xq[k * 4];
        xa[k][1] = xq[k * 4 + 1];
    }

    #pragma unroll 1
    for (int q = 0; q < Q - 2; q += 2) {
        #pragma unroll
        for (int j = 0; j < 8; j++) wb[j] = wq[(q + 1) * 1024 + j * 32];
        #pragma unroll
        for (int k = 0; k < 4; k++) {
            xc[k][0] = xq[((q + 1) * 4 + k) * 4];
            xc[k][1] = xq[((q + 1) * 4 + k) * 4 + 1];
        }
        FMA_CHUNK(wa, xa)
        #pragma unroll
        for (int j = 0; j < 8; j++) wa[j] = wq[(q + 2) * 1024 + j * 32];
        #pragma unroll
        for (int k = 0; k < 4; k++) {
            xa[k][0] = xq[((q + 2) * 4 + k) * 4];
            xa[k][1] = xq[((q + 2) * 4 + k) * 4 + 1];
        }
        FMA_CHUNK(wb, xc)
    }
    // tail: chunk Q-2 (already in wa/xa) and chunk Q-1
    #pragma unroll
    for (int j = 0; j < 8; j++) wb[j] = wq[(Q - 1) * 1024 + j * 32];
    #pragma unroll
    for (int k = 0; k < 4; k++) {
        xc[k][0] = xq[((Q - 1) * 4 + k) * 4];
        xc[k][1] = xq[((Q - 1) * 4 + k) * 4 + 1];
    }
    FMA_CHUNK(wa, xa)
    FMA_CHUNK(wb, xc)

    __syncthreads();   // all waves done READING xb before h region is overwritten
    #pragma unroll
    for (int ul = 0; ul < 2; ul++) {
        int u = u0 + ul * 32;
        float hv[8];
        #pragma unroll
        for (int r = 0; r < 8; r++) {
            float gi = acc[ul * 4 + 0][r] + bs[ul * 4 + 0];
            float gf = acc[ul * 4 + 1][r] + bs[ul * 4 + 1];
            float gg = acc[ul * 4 + 2][r] + bs[ul * 4 + 2];
            float go = acc[ul * 4 + 3][r] + bs[ul * 4 + 3];
            float cn = sigf(gf) * cr[ul][r] + sigf(gi) * tanhf(gg);
            cr[ul][r] = cn;
            hv[r] = sigf(go) * tanhf(cn);
        }
        v4 h0v, h1v;
        #pragma unroll
        for (int r = 0; r < 4; r++) { h0v[r] = hv[r]; h1v[r] = hv[4 + r]; }
        *reinterpret_cast<v4*>(dst + u * 16 + rg * 8)     = h0v;
        *reinterpret_cast<v4*>(dst + u * 16 + rg * 8 + 4) = h1v;
    }
    __syncthreads();   // h visible before next phase reads it
}

// ---------------------------------------------------------------------------
// lin phase: pred = sigmoid(h2 @ linW^T + b). Thread = 2 cols x 8 rows.
// chunk stride 256 quads; cols n0, n0+32.
// ---------------------------------------------------------------------------
__device__ __forceinline__ void lin_phase(
    const v4* __restrict__ wq, const float* __restrict__ xb,
    const float* __restrict__ linb,
    int n0, int rg, int m0, int t,
    float* __restrict__ probdst, float* __restrict__ out)
{
    float bsl[2] = { linb[n0], linb[n0 + 32] };
    float acc[2][8];
    #pragma unroll
    for (int j = 0; j < 2; j++)
        #pragma unroll
        for (int r = 0; r < 8; r++) acc[j][r] = 0.0f;

    const v4* xq = reinterpret_cast<const v4*>(xb) + rg * 2;
    v4 wa[2], wb[2], xa[4][2], xc[4][2];
    #pragma unroll
    for (int j = 0; j < 2; j++) wa[j] = wq[j * 32];
    #pragma unroll
    for (int k = 0; k < 4; k++) {
        xa[k][0] = xq[k * 4];
        xa[k][1] = xq[k * 4 + 1];
    }

    #pragma unroll 1
    for (int q = 0; q < 62; q += 2) {
        #pragma unroll
        for (int j = 0; j < 2; j++) wb[j] = wq[(q + 1) * 256 + j * 32];
        #pragma unroll
        for (int k = 0; k < 4; k++) {
            xc[k][0] = xq[((q + 1) * 4 + k) * 4];
            xc[k][1] = xq[((q + 1) * 4 + k) * 4 + 1];
        }
        #pragma unroll
        for (int k = 0; k < 4; k++)
            #pragma unroll
            for (int j = 0; j < 2; j++)
                #pragma unroll
                for (int h = 0; h < 2; h++)
                    #pragma unroll
                    for (int r = 0; r < 4; r++)
                        acc[j][h * 4 + r] += wa[j][k] * xa[k][h][r];
        #pragma unroll
        for (int j = 0; j < 2; j++) wa[j] = wq[(q + 2) * 256 + j * 32];
        #pragma unroll
        for (int k = 0; k < 4; k++) {
            xa[k][0] = xq[((q + 2) * 4 + k) * 4];
            xa[k][1] = xq[((q + 2) * 4 + k) * 4 + 1];
        }
        #pragma unroll
        for (int k = 0; k < 4; k++)
            #pragma unroll
            for (int j = 0; j < 2; j++)
                #pragma unroll
                for (int h = 0; h < 2; h++)
                    #pragma unroll
                    for (int r = 0; r < 4; r++)
                        acc[j][h * 4 + r] += wb[j][k] * xc[k][h][r];
    }
    #pragma unroll
    for (int j = 0; j < 2; j++) wb[j] = wq[63 * 256 + j * 32];
    #pragma unroll
    for (int k = 0; k < 4; k++) {
        xc[k][0] = xq[(63 * 4 + k) * 4];
        xc[k][1] = xq[(63 * 4 + k) * 4 + 1];
    }
    #pragma unroll
    for (int k = 0; k < 4; k++)
        #pragma unroll
        for (int j = 0; j < 2; j++)
            #pragma unroll
            for (int h = 0; h < 2; h++)
                #pragma unroll
                for (int r = 0; r < 4; r++)
                    acc[j][h * 4 + r] += wa[j][k] * xa[k][h][r];
    #pragma unroll
    for (int k = 0; k < 4; k++)
        #pragma unroll
        for (int j = 0; j < 2; j++)
            #pragma unroll
            for (int h = 0; h < 2; h++)
                #pragma unroll
                for (int r = 0; r < 4; r++)
                    acc[j][h * 4 + r] += wb[j][k] * xc[k][h][r];

    __syncthreads();   // everyone done reading h2; old prob no longer needed
    float pv0[8], pv1[8];
    #pragma unroll
    for (int r = 0; r < 8; r++) {
        pv0[r] = sigf(acc[0][r] + bsl[0]);
        pv1[r] = sigf(acc[1][r] + bsl[1]);
    }
    {
        v4 a0, a1, b0, b1;
        #pragma unroll
        for (int r = 0; r < 4; r++) {
            a0[r] = pv0[r]; a1[r] = pv0[4 + r];
            b0[r] = pv1[r]; b1[r] = pv1[4 + r];
        }
        *reinterpret_cast<v4*>(probdst + n0 * 16 + rg * 8)            = a0;
        *reinterpret_cast<v4*>(probdst + n0 * 16 + rg * 8 + 4)        = a1;
        *reinterpret_cast<v4*>(probdst + (n0 + 32) * 16 + rg * 8)     = b0;
        *reinterpret_cast<v4*>(probdst + (n0 + 32) * 16 + rg * 8 + 4) = b1;
    }
    #pragma unroll
    for (int r = 0; r < 8; r++) {
        long long off = (long long)(m0 + rg * 8 + r) * LDP + (long long)(t + 1) * AA;
        out[off + n0]      = pv0[r];
        out[off + n0 + 32] = pv1[r];
    }
    __syncthreads();   // prob LDS visible for argmax + next step
}

// ---------------------------------------------------------------------------
// Persistent decode kernel: 256 blocks x 16 rows, 4 waves, 30 steps fused.
// __launch_bounds__(256, 1): 1 wave/EU -> 512-VGPR budget so the w/x
// double-buffers stay in registers.
// ---------------------------------------------------------------------------
__global__ __launch_bounds__(256, 1) void decode_kernel(
    const float* __restrict__ tags,
    const float* __restrict__ bih0, const float* __restrict__ bhh0,
    const float* __restrict__ bih12, const float* __restrict__ bhh12,
    const float* __restrict__ linb,
    const float* __restrict__ ws,
    float* __restrict__ out)
{
    __shared__ float X[XROWS * 16];      // 73728 B
    __shared__ float redv[256];          // argmax partials [16 sb][16 rows]
    __shared__ int   redi[256];

    const int tid  = threadIdx.x;
    const int w    = tid >> 6;
    const int lane = tid & 63;
    const int cg   = lane & 31;
    const int rg   = lane >> 5;
    const int u0   = w * 64 + cg;
    const int m0   = blockIdx.x * 16;

    // ---- init: zero state, stage tags, one-hot(START=1) ----
    for (int i = tid; i < XROWS * 16; i += 256) X[i] = 0.0f;
    __syncthreads();
    for (int i = tid; i < 128 * 16; i += 256) {
        int m = i & 15, k = i >> 4;
        X[(256 + k) * 16 + m] = tags[(long long)(m0 + m) * 128 + k];
    }
    if (tid < 16) X[1 * 16 + tid] = 1.0f;                    // prob one-hot col 1
    for (int i = tid; i < 256 * 16; i += 256) {
        int m = i >> 8, col = i & 255;
        out[(long long)(m0 + m) * LDP + col] = (col == 1) ? 1.0f : 0.0f;
    }
    __syncthreads();

    float cr0[2][8], cr1[2][8], cr2[2][8];
    #pragma unroll
    for (int a = 0; a < 2; a++)
        #pragma unroll
        for (int b = 0; b < 8; b++) { cr0[a][b] = 0.f; cr1[a][b] = 0.f; cr2[a][b] = 0.f; }

    const v4* wsq = reinterpret_cast<const v4*>(ws);
    const v4* w0p = wsq + 0        + w * 256 + cg;
    const v4* w1p = wsq + WP1_BASE + w * 256 + cg;
    const v4* w2p = wsq + WP2_BASE + w * 256 + cg;
    const v4* wlp = wsq + WPL_BASE + w * 64  + cg;

    float* hx0 = X + 384 * 16;   // h0 rows
    float* hx1 = X + 640 * 16;   // h1 rows
    float* hx2 = X + 896 * 16;   // h2 rows

    const int arow = tid & 15, sb = tid >> 4;    // sb in 0..15
    float* outputs = out + PROB_N;

    #pragma unroll 1
    for (int t = 0; t < STEPS; t++) {
        lstm_phase<160>(w0p, X,   bih0,         bhh0,         u0, rg, cr0, hx0);
        lstm_phase<128>(w1p, hx0, bih12,        bhh12,        u0, rg, cr1, hx1);
        lstm_phase<128>(w2p, hx1, bih12 + 1024, bhh12 + 1024, u0, rg, cr2, hx2);
        lin_phase(wlp, hx2, linb, u0, rg, m0, t, X, out);

        // ---- argmax over X[0..255][arow] (prob), first-max tie rule ----
        float bv = -1.0f; int bi = 0;
        #pragma unroll
        for (int i = 0; i < 16; i++) {
            int uu = sb * 16 + i;
            float v = X[uu * 16 + arow];
            if (v > bv) { bv = v; bi = uu; }
        }
        redv[sb * 16 + arow] = bv;
        redi[sb * 16 + arow] = bi;
        __syncthreads();
        if (tid < 16) {
            float v0 = redv[tid]; int i0 = redi[tid];
            #pragma unroll 1
            for (int s = 1; s < 16; s++) {
                float v = redv[s * 16 + tid]; int ii = redi[s * 16 + tid];
                if (v > v0 || (v == v0 && ii < i0)) { v0 = v; i0 = ii; }
            }
            outputs[(long long)(m0 + tid) * STEPS + t] = (float)i0;
        }
        // no extra barrier needed: redv/redi next written only after the 8
        // barriers of step t+1's phases; prob/h reads below are read-read.
    }
}

// ---------------------------------------------------------------------------
extern "C" void kernel_launch(void* const* d_in, const int* in_sizes, int n_in,
                              void* d_out, int out_size, void* d_ws, size_t ws_size,
                              hipStream_t stream) {
    const float* tags  = (const float*)d_in[2];
    const float* Wih0  = (const float*)d_in[13];  // [1024, 384]
    const float* Whh0  = (const float*)d_in[14];  // [1024, 256]
    const float* bih0  = (const float*)d_in[15];
    const float* bhh0  = (const float*)d_in[16];
    const float* Wih12 = (const float*)d_in[17];  // [2, 1024, 256]
    const float* Whh12 = (const float*)d_in[18];
    const float* bih12 = (const float*)d_in[19];  // [2, 1024]
    const float* bhh12 = (const float*)d_in[20];
    const float* linW  = (const float*)d_in[21];  // [256, 256]
    const float* linb  = (const float*)d_in[22];

    float* out = (float*)d_out;
    float* ws  = (float*)d_ws;                    // 7.08 MB repacked weights

    repack_kernel<<<WP_TOTAL / 256, 256, 0, stream>>>(Wih0, Whh0, Wih12, Whh12,
                                                      linW, ws);
    decode_kernel<<<Bsz / 16, 256, 0, stream>>>(
        tags, bih0, bhh0, bih12, bhh12, linb, ws, out);
}